// Round 2
// baseline (4506.410 us; speedup 1.0000x reference)
//
#include <hip/hip_runtime.h>
#include <cstdint>
#include <cstddef>

typedef _Float16 half_t;
typedef half_t half2_t __attribute__((ext_vector_type(2)));

static constexpr int TTs = 2048;   // timesteps
static constexpr int BBn = 64;     // batch
static constexpr int DINn = 64;    // input dim
static constexpr int HPn  = 256;   // proj dim
static constexpr int U0c = 135, C0c = 391, R0c = 405;   // layer0: units, concat, 3*units
static constexpr int U1c = 89,  C1c = 224, R1c = 267;   // layer1
static constexpr int U2c = 32,  C2c = 121, R2c = 96;    // layer2
static constexpr int Z0c = 200;                          // [x(64)|h0(135)|pad(1)] halfs
static constexpr size_t BTn = (size_t)BBn * TTs;        // 131072

// ---------------- math helpers ----------------
__device__ __forceinline__ float tanh_f(float x) {
    return 1.f - __fdividef(2.f, __expf(2.f * x) + 1.f);
}
__device__ __forceinline__ float sigm_f(float x) {
    return __fdividef(1.f, 1.f + __expf(-x));
}

// ---------------- mask dtype probe ----------------
__device__ __forceinline__ int mask_mode(const unsigned char* mp) {
    const unsigned* wp = (const unsigned*)mp;
    bool all01 = true, allf = true;
    for (int k = 0; k < 64; ++k) {
        unsigned w = wp[k];
        all01 = all01 && (w == 0u || w == 1u);
        allf  = allf  && (w == 0u || w == 0x3F800000u);
    }
    if (all01) return 0;   // int32
    if (allf)  return 1;   // float32
    return 2;              // uint8/bool
}
__device__ __forceinline__ bool mget(const unsigned char* mp, int mode, int idx) {
    if (mode == 0) return ((const int*)mp)[idx] != 0;
    if (mode == 1) return ((const float*)mp)[idx] != 0.f;
    return mp[idx] != 0;
}

// ---------------- prep: stack + mask weights ----------------
// rows [ff1m ; ff2m ; (ta+tb)] (3u x c), cols split at `split` into outA/outB.
__global__ void k_stack(const float* __restrict__ Wff1, const float* __restrict__ bff1,
                        const float* __restrict__ Wff2, const float* __restrict__ bff2,
                        const float* __restrict__ Wta,  const float* __restrict__ bta,
                        const float* __restrict__ Wtb,  const float* __restrict__ btb,
                        const unsigned char* __restrict__ maskraw,
                        int u, int c, int split,
                        float* __restrict__ outA, float* __restrict__ outB,
                        float* __restrict__ bias_out)
{
    const int mode = mask_mode(maskraw);
    const int total = 3 * u * c + 3 * u;
    for (int idx = blockIdx.x * blockDim.x + threadIdx.x; idx < total;
         idx += gridDim.x * blockDim.x) {
        if (idx < 3 * u * c) {
            int m = idx / (u * c);
            int rem = idx - m * u * c;
            int r = rem / c;
            int k = rem - r * c;
            float v;
            if (m == 2) {
                v = Wta[r * c + k] + Wtb[r * c + k];
            } else {
                bool mk = mget(maskraw, mode, r * c + k);
                float w = (m == 0) ? Wff1[r * c + k] : Wff2[r * c + k];
                v = mk ? w : 0.f;
            }
            int R = m * u + r;
            if (k < split) outA[(size_t)R * split + k] = v;
            else           outB[(size_t)R * (c - split) + (k - split)] = v;
        } else {
            int j = idx - 3 * u * c;
            int m = j / u, r = j - m * u;
            bias_out[j] = (m == 0) ? bff1[r] : ((m == 1) ? bff2[r] : (bta[r] + btb[r]));
        }
    }
}

// ---------------- prep: Wcomb = Wx0s (405x256) @ Wp (256x64) ----------------
__global__ void k_comb(const float* __restrict__ Wx0s, const float* __restrict__ Wp,
                       float* __restrict__ Wcomb)
{
    const int r = blockIdx.x;     // 0..404
    const int d = threadIdx.x;    // 0..63
    float acc = 0.f;
    for (int k = 0; k < HPn; ++k) acc += Wx0s[(size_t)r * HPn + k] * Wp[(size_t)k * DINn + d];
    Wcomb[(size_t)r * DINn + d] = acc;
}

// ---------------- prep: folded bias + Wh2 transpose ----------------
__global__ void k_biasc(const float* __restrict__ Wx0s, const float* __restrict__ bp,
                        const float* __restrict__ b0, float* __restrict__ b0c,
                        const float* __restrict__ Wh2, float* __restrict__ Wh2T)
{
    const int i = blockIdx.x * blockDim.x + threadIdx.x;
    if (i < R0c) {
        float a = b0[i];
        for (int k = 0; k < HPn; ++k) a += Wx0s[(size_t)i * HPn + k] * bp[k];
        b0c[i] = a;
    }
    if (i < HPn * 32) {
        int h = i >> 5, o = i & 31;
        Wh2T[i] = Wh2[(size_t)o * HPn + h];   // Wh2 is (32,256)
    }
}

// ---------------- the recurrent scan: 64 blocks x 512 threads ----------------
// All weights register-resident as packed half2; fp32 accumulation via
// v_dot2_f32_f16. Layer0 row = [Wcomb(64) | Wh0(135)] acting on
// z0 = [x_t | h0] in LDS. Workspace footprint: ~1 MB total.
__global__ __launch_bounds__(512, 2) void k_scan(
    const float* __restrict__ Wcb,    // (405,64)   x-part (folded through Wp)
    const float* __restrict__ Wh0s,   // (405,135)  h-part of layer0, stacked
    const float* __restrict__ b0c,    // (405)      folded bias
    const float* __restrict__ W1s,    // (267,224)
    const float* __restrict__ b1s,    // (267)
    const float* __restrict__ W2s,    // (96,121)
    const float* __restrict__ b2s,    // (96)
    const float* __restrict__ x,      // (B,T,64)
    float* __restrict__ cfc)          // (B,T,32) -> d_out
{
    const int t = threadIdx.x;
    const int b = blockIdx.x;

    __shared__ float4 z0v[25];   // 200 halfs: [x:64][h0:135][pad:1]
    __shared__ float4 z1v[28];   // 224 halfs: [h0:135][h1:89]
    __shared__ float4 z2v[16];   // 128 halfs: [h1:89][h2:32][pad]
    __shared__ float  ybuf[408];

    half_t* z0h = (half_t*)z0v;
    half_t* z1h = (half_t*)z1v;
    half_t* z2h = (half_t*)z2v;

    if (t < 25) z0v[t] = make_float4(0.f, 0.f, 0.f, 0.f);
    if (t < 28) z1v[t] = make_float4(0.f, 0.f, 0.f, 0.f);
    if (t < 16) z2v[t] = make_float4(0.f, 0.f, 0.f, 0.f);

    // ---- register-resident weights, packed fp16 ----
    const bool act0 = t < R0c;          // one full 199-col extended row per thread
    half2_t w0[100];
#pragma unroll
    for (int k = 0; k < 100; ++k) {
        int c0 = 2 * k, c1 = 2 * k + 1;
        float lo = 0.f, hi = 0.f;
        if (act0) {
            lo = (c0 < DINn) ? Wcb[(size_t)t * DINn + c0]
                             : ((c0 < DINn + U0c) ? Wh0s[(size_t)t * U0c + (c0 - DINn)] : 0.f);
            hi = (c1 < DINn) ? Wcb[(size_t)t * DINn + c1]
                             : ((c1 < DINn + U0c) ? Wh0s[(size_t)t * U0c + (c1 - DINn)] : 0.f);
        }
        half2_t p; p[0] = (half_t)lo; p[1] = (half_t)hi;
        w0[k] = p;
    }
    // layer1 main: rows 0..255 (t>>1), half-row of 112 cols each
    const int r1m = t >> 1;
    const int c1b = (t & 1) * 112;
    half2_t w1[56];
#pragma unroll
    for (int k = 0; k < 56; ++k) {
        half2_t p;
        p[0] = (half_t)W1s[(size_t)r1m * C1c + c1b + 2 * k];
        p[1] = (half_t)W1s[(size_t)r1m * C1c + c1b + 2 * k + 1];
        w1[k] = p;
    }
    // layer1 leftover rows 256..266: 32 threads/row, 8 cols each (threads 0..351)
    const bool actL = t < 352;
    const int rL  = 256 + (t >> 5);
    const int cLb = (t & 31) * 8;
    half2_t wLv[4];
#pragma unroll
    for (int k = 0; k < 4; ++k) {
        int c0i = cLb + 2 * k, c1i = cLb + 2 * k + 1;
        float lo = (actL && c0i < C1c) ? W1s[(size_t)rL * C1c + c0i] : 0.f;
        float hi = (actL && c1i < C1c) ? W1s[(size_t)rL * C1c + c1i] : 0.f;
        half2_t p; p[0] = (half_t)lo; p[1] = (half_t)hi;
        wLv[k] = p;
    }
    // layer2: rows 0..95, 4 threads/row, 32 cols each (threads 0..383)
    const bool act2 = t < 384;
    const int r2  = t >> 2;
    const int c2b = (t & 3) * 32;
    half2_t w2[16];
#pragma unroll
    for (int k = 0; k < 16; ++k) {
        int c0i = c2b + 2 * k, c1i = c2b + 2 * k + 1;
        float lo = (act2 && c0i < C2c) ? W2s[(size_t)r2 * C2c + c0i] : 0.f;
        float hi = (act2 && c1i < C2c) ? W2s[(size_t)r2 * C2c + c1i] : 0.f;
        half2_t p; p[0] = (half_t)lo; p[1] = (half_t)hi;
        w2[k] = p;
    }
    float bc0 = 0.f, bc1 = 0.f, bc2 = 0.f;
    if (t < U0c) { bc0 = b0c[t]; bc1 = b0c[t + U0c]; bc2 = b0c[t + 2 * U0c]; }
    float b1f = 0.f, b1g = 0.f, b1t = 0.f;
    if (t < U1c) { b1f = b1s[t]; b1g = b1s[t + U1c]; b1t = b1s[t + 2 * U1c]; }
    float b2f = 0.f, b2g = 0.f, b2t = 0.f;
    if (t < U2c) { b2f = b2s[t]; b2g = b2s[t + U2c]; b2t = b2s[t + 2 * U2c]; }

    const float* xb = x + (size_t)b * TTs * DINn;
    float* cfb = cfc + (size_t)b * TTs * 32;
    const int xl = t - 448;             // threads 448..511 stage x

    __syncthreads();
    if (xl >= 0) z0h[xl] = (half_t)xb[xl];   // x(0)
    __syncthreads();

#pragma unroll 1
    for (int ts = 0; ts < TTs; ++ts) {
        // stage x(ts+1): issue global load now (threads 448+ idle in phase A)
        float xnext = 0.f;
        if (xl >= 0) {
            int tn = (ts + 1 < TTs) ? ts + 1 : ts;
            xnext = xb[(size_t)tn * DINn + xl];
        }
        // ---- phase A: layer0 extended matvec over z0 = [x|h0] ----
        if (act0) {
            float a0 = 0.f, a1 = 0.f, a2 = 0.f, a3 = 0.f;
#pragma unroll
            for (int j = 0; j < 25; ++j) {
                float4 v = z0v[j];
                a0 = __builtin_amdgcn_fdot2(w0[4 * j + 0], __builtin_bit_cast(half2_t, v.x), a0, false);
                a1 = __builtin_amdgcn_fdot2(w0[4 * j + 1], __builtin_bit_cast(half2_t, v.y), a1, false);
                a2 = __builtin_amdgcn_fdot2(w0[4 * j + 2], __builtin_bit_cast(half2_t, v.z), a2, false);
                a3 = __builtin_amdgcn_fdot2(w0[4 * j + 3], __builtin_bit_cast(half2_t, v.w), a3, false);
            }
            ybuf[t] = (a0 + a1) + (a2 + a3);
        }
        __syncthreads();
        // ---- phase B: combine layer0; write new h0 and x(ts+1) into z0 ----
        if (t < U0c) {
            float y1 = ybuf[t]           + bc0;
            float y2 = ybuf[t + U0c]     + bc1;
            float yt = ybuf[t + 2 * U0c] + bc2;
            float f1 = tanh_f(y1), f2 = tanh_f(y2), ti = sigm_f(yt);
            float hn = f1 + ti * (f2 - f1);
            half_t hh = (half_t)hn;
            z0h[DINn + t] = hh;
            z1h[t] = hh;
        }
        if (xl >= 0) z0h[xl] = (half_t)xnext;
        __syncthreads();
        // ---- phase C: layer1 matvec ----
        {
            float a0 = 0.f, a1 = 0.f, a2 = 0.f, a3 = 0.f;
            const float4* zp = z1v + (t & 1) * 14;
#pragma unroll
            for (int j = 0; j < 14; ++j) {
                float4 v = zp[j];
                a0 = __builtin_amdgcn_fdot2(w1[4 * j + 0], __builtin_bit_cast(half2_t, v.x), a0, false);
                a1 = __builtin_amdgcn_fdot2(w1[4 * j + 1], __builtin_bit_cast(half2_t, v.y), a1, false);
                a2 = __builtin_amdgcn_fdot2(w1[4 * j + 2], __builtin_bit_cast(half2_t, v.z), a2, false);
                a3 = __builtin_amdgcn_fdot2(w1[4 * j + 3], __builtin_bit_cast(half2_t, v.w), a3, false);
            }
            float s = (a0 + a1) + (a2 + a3);
            s += __shfl_xor(s, 1, 64);
            if ((t & 1) == 0) ybuf[r1m] = s;
        }
        if (actL) {
            float4 v = z1v[t & 31];
            float aL = 0.f;
            aL = __builtin_amdgcn_fdot2(wLv[0], __builtin_bit_cast(half2_t, v.x), aL, false);
            aL = __builtin_amdgcn_fdot2(wLv[1], __builtin_bit_cast(half2_t, v.y), aL, false);
            aL = __builtin_amdgcn_fdot2(wLv[2], __builtin_bit_cast(half2_t, v.z), aL, false);
            aL = __builtin_amdgcn_fdot2(wLv[3], __builtin_bit_cast(half2_t, v.w), aL, false);
            aL += __shfl_xor(aL, 1, 64);
            aL += __shfl_xor(aL, 2, 64);
            aL += __shfl_xor(aL, 4, 64);
            aL += __shfl_xor(aL, 8, 64);
            aL += __shfl_xor(aL, 16, 64);
            if ((t & 31) == 0) ybuf[rL] = aL;
        }
        __syncthreads();
        // ---- phase D: combine layer1 ----
        if (t < U1c) {
            float y1 = ybuf[t] + b1f;
            float y2 = ybuf[t + U1c] + b1g;
            float yt = ybuf[t + 2 * U1c] + b1t;
            float f1 = tanh_f(y1), f2 = tanh_f(y2), ti = sigm_f(yt);
            float hn = f1 + ti * (f2 - f1);
            half_t hh = (half_t)hn;
            z1h[U0c + t] = hh;
            z2h[t] = hh;
        }
        __syncthreads();
        // ---- phase E: layer2 matvec ----
        if (act2) {
            float a0 = 0.f, a1 = 0.f, a2 = 0.f, a3 = 0.f;
            const float4* zp = z2v + (t & 3) * 4;
#pragma unroll
            for (int j = 0; j < 4; ++j) {
                float4 v = zp[j];
                a0 = __builtin_amdgcn_fdot2(w2[4 * j + 0], __builtin_bit_cast(half2_t, v.x), a0, false);
                a1 = __builtin_amdgcn_fdot2(w2[4 * j + 1], __builtin_bit_cast(half2_t, v.y), a1, false);
                a2 = __builtin_amdgcn_fdot2(w2[4 * j + 2], __builtin_bit_cast(half2_t, v.z), a2, false);
                a3 = __builtin_amdgcn_fdot2(w2[4 * j + 3], __builtin_bit_cast(half2_t, v.w), a3, false);
            }
            float s = (a0 + a1) + (a2 + a3);
            s += __shfl_xor(s, 1, 64);
            s += __shfl_xor(s, 2, 64);
            if ((t & 3) == 0) ybuf[r2] = s;
        }
        __syncthreads();
        // ---- phase F: combine layer2 (motor) + emit ----
        if (t < U2c) {
            float y1 = ybuf[t] + b2f;
            float y2 = ybuf[t + U2c] + b2g;
            float yt = ybuf[t + 2 * U2c] + b2t;
            float f1 = tanh_f(y1), f2 = tanh_f(y2), ti = sigm_f(yt);
            float hn = f1 + ti * (f2 - f1);
            z2h[U1c + t] = (half_t)hn;
            cfb[(size_t)ts * 32 + t] = hn;
        }
        __syncthreads();
    }
}

// ---------------- head: in-place gelu(cfc@Wh1.T+bh1)@Wh2.T + bh2 ----------------
__global__ __launch_bounds__(256) void k_head(float* io,
                                              const float* __restrict__ Wh1,
                                              const float* __restrict__ bh1,
                                              const float* __restrict__ Wh2T,
                                              const float* __restrict__ bh2)
{
    const int bt = blockIdx.x * 256 + threadIdx.x;
    float c32[32];
    const float4* cp = (const float4*)(io + (size_t)bt * 32);
#pragma unroll
    for (int k = 0; k < 8; ++k) {
        float4 v = cp[k];
        c32[4 * k] = v.x; c32[4 * k + 1] = v.y; c32[4 * k + 2] = v.z; c32[4 * k + 3] = v.w;
    }
    float acc[32];
#pragma unroll
    for (int o = 0; o < 32; ++o) acc[o] = bh2[o];
#pragma unroll 1
    for (int h = 0; h < HPn; ++h) {
        float s = bh1[h];
        const float* w1r = Wh1 + (size_t)h * 32;
#pragma unroll
        for (int k = 0; k < 32; ++k) s += c32[k] * w1r[k];
        float g = 0.5f * s * (1.f + erff(s * 0.70710678118654752440f));   // exact gelu
        const float* w2r = Wh2T + (size_t)h * 32;
#pragma unroll
        for (int o = 0; o < 32; ++o) acc[o] += g * w2r[o];
    }
    float4* op = (float4*)(io + (size_t)bt * 32);
#pragma unroll
    for (int k = 0; k < 8; ++k) {
        float4 v;
        v.x = acc[4 * k]; v.y = acc[4 * k + 1]; v.z = acc[4 * k + 2]; v.w = acc[4 * k + 3];
        op[k] = v;
    }
}

// ---------------- launch ----------------
extern "C" void kernel_launch(void* const* d_in, const int* in_sizes, int n_in,
                              void* d_out, int out_size, void* d_ws, size_t ws_size,
                              hipStream_t stream)
{
    (void)in_sizes; (void)n_in; (void)out_size; (void)ws_size;
    const float* x      = (const float*)d_in[0];
    const float* Wp     = (const float*)d_in[1];
    const float* bp     = (const float*)d_in[2];
    const float* Wff1_0 = (const float*)d_in[3];
    const float* bff1_0 = (const float*)d_in[4];
    const float* Wff2_0 = (const float*)d_in[5];
    const float* bff2_0 = (const float*)d_in[6];
    const float* Wta_0  = (const float*)d_in[7];
    const float* bta_0  = (const float*)d_in[8];
    const float* Wtb_0  = (const float*)d_in[9];
    const float* btb_0  = (const float*)d_in[10];
    const unsigned char* mask_0 = (const unsigned char*)d_in[11];
    const float* Wff1_1 = (const float*)d_in[12];
    const float* bff1_1 = (const float*)d_in[13];
    const float* Wff2_1 = (const float*)d_in[14];
    const float* bff2_1 = (const float*)d_in[15];
    const float* Wta_1  = (const float*)d_in[16];
    const float* bta_1  = (const float*)d_in[17];
    const float* Wtb_1  = (const float*)d_in[18];
    const float* btb_1  = (const float*)d_in[19];
    const unsigned char* mask_1 = (const unsigned char*)d_in[20];
    const float* Wff1_2 = (const float*)d_in[21];
    const float* bff1_2 = (const float*)d_in[22];
    const float* Wff2_2 = (const float*)d_in[23];
    const float* bff2_2 = (const float*)d_in[24];
    const float* Wta_2  = (const float*)d_in[25];
    const float* bta_2  = (const float*)d_in[26];
    const float* Wtb_2  = (const float*)d_in[27];
    const float* btb_2  = (const float*)d_in[28];
    const unsigned char* mask_2 = (const unsigned char*)d_in[29];
    const float* Wh1    = (const float*)d_in[30];
    const float* bh1    = (const float*)d_in[31];
    const float* Wh2    = (const float*)d_in[32];
    const float* bh2    = (const float*)d_in[33];

    // workspace: weights only (~1.06 MB)
    float* ws = (float*)d_ws;
    size_t o = 0;
    float* Wh0s = ws + o; o += (size_t)R0c * U0c;    // 54675
    float* Wx0s = ws + o; o += (size_t)R0c * HPn;    // 103680
    float* b0s  = ws + o; o += R0c;
    float* Wcb  = ws + o; o += (size_t)R0c * DINn;   // 25920
    float* b0c  = ws + o; o += R0c;
    float* W1s  = ws + o; o += (size_t)R1c * C1c;    // 59808
    float* b1s  = ws + o; o += R1c;
    float* W2s  = ws + o; o += (size_t)R2c * C2c;    // 11616
    float* b2s  = ws + o; o += R2c;
    float* Wh2T = ws + o; o += (size_t)HPn * 32;     // 8192

    // prep: stacked+masked weights (fold ta+tb); split layer0 into x/h parts
    k_stack<<<128, 256, 0, stream>>>(Wff1_0, bff1_0, Wff2_0, bff2_0, Wta_0, bta_0, Wtb_0, btb_0,
                                     mask_0, U0c, C0c, HPn, Wx0s, Wh0s, b0s);
    k_stack<<<64, 256, 0, stream>>>(Wff1_1, bff1_1, Wff2_1, bff2_1, Wta_1, bta_1, Wtb_1, btb_1,
                                    mask_1, U1c, C1c, C1c, W1s, W1s, b1s);
    k_stack<<<16, 256, 0, stream>>>(Wff1_2, bff1_2, Wff2_2, bff2_2, Wta_2, bta_2, Wtb_2, btb_2,
                                    mask_2, U2c, C2c, C2c, W2s, W2s, b2s);
    // prep: collapse input projection through layer0 x-part
    k_comb<<<R0c, DINn, 0, stream>>>(Wx0s, Wp, Wcb);
    k_biasc<<<32, 256, 0, stream>>>(Wx0s, bp, b0s, b0c, Wh2, Wh2T);
    // the serial scan (motor outputs -> d_out)
    k_scan<<<BBn, 512, 0, stream>>>(Wcb, Wh0s, b0c, W1s, b1s, W2s, b2s, x, (float*)d_out);
    // output head, in place on d_out
    k_head<<<(int)(BTn / 256), 256, 0, stream>>>((float*)d_out, Wh1, bh1, Wh2T, bh2);
}